// Round 1
// baseline (395.417 us; speedup 1.0000x reference)
//
#include <hip/hip_runtime.h>

typedef unsigned short ushort;
typedef __bf16 bf16x8 __attribute__((ext_vector_type(8)));
typedef float f32x4 __attribute__((ext_vector_type(4)));
typedef unsigned short us8v __attribute__((ext_vector_type(8)));

__device__ __forceinline__ ushort f2bf(float f) {
  unsigned u = __builtin_bit_cast(unsigned, f);
  u += 0x7FFFu + ((u >> 16) & 1u);
  return (ushort)(u >> 16);
}

__device__ __forceinline__ bf16x8 ld_bf16x8(const ushort* p) {
  uint4 v = *(const uint4*)p;
  return __builtin_bit_cast(bf16x8, v);
}

// ---------------- pack X fp32 -> bf16 ----------------
__global__ __launch_bounds__(256) void pack_x(const float* __restrict__ in,
                                              ushort* __restrict__ out) {
  long i = (long)blockIdx.x * 256 + threadIdx.x;
  const float4* s = (const float4*)in;
  float4 a = s[i * 2], b = s[i * 2 + 1];
  us8v o;
  o[0] = f2bf(a.x); o[1] = f2bf(a.y); o[2] = f2bf(a.z); o[3] = f2bf(a.w);
  o[4] = f2bf(b.x); o[5] = f2bf(b.y); o[6] = f2bf(b.z); o[7] = f2bf(b.w);
  *(us8v*)&out[i * 8] = o;
}

// ---------------- transpose+pack weights: dst[c][r] = src[r][c]*scale (bf16) ----
__global__ __launch_bounds__(256) void transpose_pack(
    const float* __restrict__ src, ushort* __restrict__ dst,
    int sC, int dLd, long sBatch, long dBatch, float scale) {
  src += (long)blockIdx.z * sBatch;
  dst += (long)blockIdx.z * dBatch;
  const int r0 = blockIdx.y * 64, c0 = blockIdx.x * 64;
  __shared__ ushort T[64 * 68];
  const int t = threadIdx.x;
#pragma unroll
  for (int i = 0; i < 4; ++i) {
    int ch = t + 256 * i;
    int r = ch >> 4, c4 = ch & 15;
    float4 v = *(const float4*)&src[(long)(r0 + r) * sC + c0 + c4 * 4];
    T[(c4 * 4 + 0) * 68 + r] = f2bf(v.x * scale);
    T[(c4 * 4 + 1) * 68 + r] = f2bf(v.y * scale);
    T[(c4 * 4 + 2) * 68 + r] = f2bf(v.z * scale);
    T[(c4 * 4 + 3) * 68 + r] = f2bf(v.w * scale);
  }
  __syncthreads();
#pragma unroll
  for (int i = 0; i < 4; ++i) {
    int ch = t + 256 * i;
    int c = ch >> 4, r4 = ch & 15;
    ushort4 o;
    o.x = T[c * 68 + r4 * 4 + 0];
    o.y = T[c * 68 + r4 * 4 + 1];
    o.z = T[c * 68 + r4 * 4 + 2];
    o.w = T[c * 68 + r4 * 4 + 3];
    *(ushort4*)&dst[(long)(c0 + c) * dLd + r0 + r4 * 4] = o;
  }
}

// ---------------- 128x128 bf16 MFMA GEMM, C = A[M,K] * Bt[N,K]^T ----------------
// EPI 0: scatter to Q/K ([B,H,S,64], Q prescaled via weights) and Vt ([B,D,S])
// EPI 1: bf16 row-major C (+batch)
// EPI 2: fp32 row-major C
template <int EPI, bool CAUSAL>
__global__ __launch_bounds__(256) void gemm128(
    const ushort* __restrict__ A, const ushort* __restrict__ Bt,
    int M, int N, int K, long aB, long bB,
    ushort* __restrict__ O_q, ushort* __restrict__ O_k, ushort* __restrict__ O_v,
    ushort* __restrict__ O_b, long oB,
    float* __restrict__ O_f) {
  __shared__ __align__(16) ushort As[128 * 72];
  __shared__ __align__(16) ushort Bs[128 * 72];
  const int tid = threadIdx.x;
  const int lane = tid & 63, w = tid >> 6;
  const int lr = lane & 15, lg = lane >> 4;
  const int row0 = blockIdx.y * 128, col0 = blockIdx.x * 128;
  const int z = blockIdx.z;
  A += (long)z * aB;
  Bt += (long)z * bB;
  const int wr = (w >> 1) * 64, wc = (w & 1) * 64;

  f32x4 acc[4][4] = {};
  const int kmax = CAUSAL ? (K < row0 + 128 ? K : row0 + 128) : K;
  for (int k0 = 0; k0 < kmax; k0 += 64) {
    __syncthreads();
#pragma unroll
    for (int i = 0; i < 4; ++i) {
      int ch = tid + 256 * i, r = ch >> 3, c = ch & 7;
      *(uint4*)&As[r * 72 + c * 8] = *(const uint4*)&A[(long)(row0 + r) * K + k0 + c * 8];
      *(uint4*)&Bs[r * 72 + c * 8] = *(const uint4*)&Bt[(long)(col0 + r) * K + k0 + c * 8];
    }
    __syncthreads();
#pragma unroll
    for (int kk = 0; kk < 2; ++kk) {
      bf16x8 af[4], bfr[4];
#pragma unroll
      for (int m = 0; m < 4; ++m)
        af[m] = ld_bf16x8(&As[(wr + m * 16 + lr) * 72 + kk * 32 + lg * 8]);
#pragma unroll
      for (int n = 0; n < 4; ++n)
        bfr[n] = ld_bf16x8(&Bs[(wc + n * 16 + lr) * 72 + kk * 32 + lg * 8]);
#pragma unroll
      for (int m = 0; m < 4; ++m)
#pragma unroll
        for (int n = 0; n < 4; ++n)
          acc[m][n] = __builtin_amdgcn_mfma_f32_16x16x32_bf16(af[m], bfr[n], acc[m][n], 0, 0, 0);
    }
  }

#pragma unroll
  for (int m = 0; m < 4; ++m)
#pragma unroll
    for (int n = 0; n < 4; ++n)
#pragma unroll
      for (int r = 0; r < 4; ++r) {
        int gr = row0 + wr + m * 16 + lg * 4 + r;
        int gc = col0 + wc + n * 16 + lr;
        float v = acc[m][n][r];
        if (EPI == 0) {
          int b = gr >> 10, s = gr & 1023;
          if (gc < 1024) {
            int h = gc >> 6, kq = gc & 63;
            O_q[(((long)(b * 16 + h) << 10) + s) * 64 + kq] = f2bf(v);
          } else if (gc < 2048) {
            int n2 = gc - 1024;
            int h = n2 >> 6, kq = n2 & 63;
            O_k[(((long)(b * 16 + h) << 10) + s) * 64 + kq] = f2bf(v);
          } else {
            int e = gc - 2048;
            O_v[((long)(b << 10) + e) * 1024 + s] = f2bf(v);
          }
        } else if (EPI == 1) {
          (O_b + (long)z * oB)[(long)gr * N + gc] = f2bf(v);
        } else {
          O_f[(long)gr * N + gc] = v;
        }
      }
}

// ---------------- fused masked softmax, head-averaged attention ----------------
// grid (32, B): block pairs q-tiles (p, 63-p), 16 q-rows each, loops all 16 heads.
__global__ __launch_bounds__(256, 1) void attn16(
    const ushort* __restrict__ Qb, const ushort* __restrict__ Kb,
    const float* __restrict__ mask, float* __restrict__ attn_out,
    ushort* __restrict__ attnb) {
  __shared__ __align__(16) ushort Qs[16 * 16 * 72];
  __shared__ __align__(16) ushort Ks[128 * 72];
  __shared__ float redA[4][16];
  __shared__ float redB[4][16];
  const int tid = threadIdx.x;
  const int lane = tid & 63, w = tid >> 6;
  const int lr = lane & 15, lg = lane >> 4;
  const int b = blockIdx.y;

#pragma unroll 1
  for (int pi = 0; pi < 2; ++pi) {
    const int qt = pi ? (63 - (int)blockIdx.x) : (int)blockIdx.x;
    const int q0 = qt * 16;
    const int NT = (q0 >> 7) + 1;  // s-tiles of 128 needed for causal rows

    __syncthreads();
#pragma unroll
    for (int i = 0; i < 8; ++i) {
      int ch = tid + 256 * i;
      int h = ch >> 7, row = (ch >> 3) & 15, c = ch & 7;
      *(uint4*)&Qs[(h * 16 + row) * 72 + c * 8] =
          *(const uint4*)&Qb[(((long)(b * 16 + h) << 10) + q0 + row) * 64 + c * 8];
    }
    float mq[4], ms[8][2];
#pragma unroll
    for (int r = 0; r < 4; ++r) mq[r] = mask[b * 1024 + q0 + lg * 4 + r];
#pragma unroll
    for (int t = 0; t < 8; ++t)
#pragma unroll
      for (int ni = 0; ni < 2; ++ni)
        ms[t][ni] = mask[b * 1024 + t * 128 + w * 32 + ni * 16 + lr];
    __syncthreads();

    f32x4 acc[8][2] = {};
#pragma unroll 1
    for (int h = 0; h < 16; ++h) {
      f32x4 sc[8][2];
#pragma unroll
      for (int t = 0; t < 8; ++t) {
        if (t < NT) {
          __syncthreads();
#pragma unroll
          for (int i = 0; i < 4; ++i) {
            int ch = tid + 256 * i, r = ch >> 3, c = ch & 7;
            *(uint4*)&Ks[r * 72 + c * 8] =
                *(const uint4*)&Kb[(((long)(b * 16 + h) << 10) + t * 128 + r) * 64 + c * 8];
          }
          __syncthreads();
#pragma unroll
          for (int ni = 0; ni < 2; ++ni) {
            f32x4 d = {};
#pragma unroll
            for (int kk = 0; kk < 2; ++kk) {
              bf16x8 af = ld_bf16x8(&Qs[(h * 16 + lr) * 72 + kk * 32 + lg * 8]);
              bf16x8 bfr = ld_bf16x8(&Ks[(w * 32 + ni * 16 + lr) * 72 + kk * 32 + lg * 8]);
              d = __builtin_amdgcn_mfma_f32_16x16x32_bf16(af, bfr, d, 0, 0, 0);
            }
            sc[t][ni] = d;
          }
        }
      }
      // mask + row max
      float pm[4] = {-1e30f, -1e30f, -1e30f, -1e30f};
#pragma unroll
      for (int t = 0; t < 8; ++t)
        if (t < NT)
#pragma unroll
          for (int ni = 0; ni < 2; ++ni) {
            int s = t * 128 + w * 32 + ni * 16 + lr;
#pragma unroll
            for (int r = 0; r < 4; ++r) {
              int q = q0 + lg * 4 + r;
              float badm = 1.0f - mq[r] * ms[t][ni];
              float v = sc[t][ni][r] - 1e9f * badm;
              v = (s <= q) ? v : -1e30f;
              sc[t][ni][r] = v;
              pm[r] = fmaxf(pm[r], v);
            }
          }
#pragma unroll
      for (int r = 0; r < 4; ++r)
#pragma unroll
        for (int off = 1; off < 16; off <<= 1)
          pm[r] = fmaxf(pm[r], __shfl_xor(pm[r], off));
      if (lr == 0) {
#pragma unroll
        for (int r = 0; r < 4; ++r) redA[w][lg * 4 + r] = pm[r];
      }
      __syncthreads();
      float mx[4], ps[4] = {0.f, 0.f, 0.f, 0.f};
#pragma unroll
      for (int r = 0; r < 4; ++r)
        mx[r] = fmaxf(fmaxf(redA[0][lg * 4 + r], redA[1][lg * 4 + r]),
                      fmaxf(redA[2][lg * 4 + r], redA[3][lg * 4 + r]));
#pragma unroll
      for (int t = 0; t < 8; ++t)
        if (t < NT)
#pragma unroll
          for (int ni = 0; ni < 2; ++ni)
#pragma unroll
            for (int r = 0; r < 4; ++r) {
              float e = __expf(sc[t][ni][r] - mx[r]);
              sc[t][ni][r] = e;
              ps[r] += e;
            }
#pragma unroll
      for (int r = 0; r < 4; ++r)
#pragma unroll
        for (int off = 1; off < 16; off <<= 1)
          ps[r] += __shfl_xor(ps[r], off);
      if (lr == 0) {
#pragma unroll
        for (int r = 0; r < 4; ++r) redB[w][lg * 4 + r] = ps[r];
      }
      __syncthreads();
#pragma unroll
      for (int r = 0; r < 4; ++r) {
        float tot = redB[0][lg * 4 + r] + redB[1][lg * 4 + r] +
                    redB[2][lg * 4 + r] + redB[3][lg * 4 + r];
        float rinv = 1.0f / tot;
#pragma unroll
        for (int t = 0; t < 8; ++t)
          if (t < NT)
#pragma unroll
            for (int ni = 0; ni < 2; ++ni)
              acc[t][ni][r] += sc[t][ni][r] * rinv;
      }
    }  // heads

    // write fp32 attn_avg (d_out) + bf16 copy (ws); untouched tiles are exact zeros
#pragma unroll
    for (int t = 0; t < 8; ++t)
#pragma unroll
      for (int ni = 0; ni < 2; ++ni) {
        int s = t * 128 + w * 32 + ni * 16 + lr;
#pragma unroll
        for (int r = 0; r < 4; ++r) {
          int q = q0 + lg * 4 + r;
          float v = acc[t][ni][r] * 0.0625f;
          long o = ((long)(b * 1024 + q) << 10) + s;
          attn_out[o] = v;
          attnb[o] = f2bf(v);
        }
      }
  }
}

// ---------------- launch ----------------
extern "C" void kernel_launch(void* const* d_in, const int* in_sizes, int n_in,
                              void* d_out, int out_size, void* d_ws, size_t ws_size,
                              hipStream_t stream) {
  const float* inputs = (const float*)d_in[0];
  const float* mask   = (const float*)d_in[1];
  const float* W_q    = (const float*)d_in[2];
  const float* W_k    = (const float*)d_in[3];
  const float* W_v    = (const float*)d_in[4];
  const float* W_o    = (const float*)d_in[5];
  float* out = (float*)d_out;

  ushort* Xb    = (ushort*)d_ws;            // [8192][1024]
  ushort* WqkvT = Xb + 8192L * 1024;        // [3072][1024]  (B^T layout)
  ushort* WoT   = WqkvT + 3072L * 1024;     // [1024][1024]
  ushort* Qb    = WoT + 1024L * 1024;       // [B,H,S,64]
  ushort* Kb    = Qb + 8L * 16 * 1024 * 64; // [B,H,S,64]
  ushort* Vt    = Kb + 8L * 16 * 1024 * 64; // [B,D,S]
  ushort* attnb = Vt + 8L * 1024 * 1024;    // [B,S,S]
  ushort* Houtb = attnb + 8L * 1024 * 1024; // [B,S,D]

  pack_x<<<4096, 256, 0, stream>>>(inputs, Xb);
  // W_q: per-head [1024][64] -> rows h*64+kq of WqkvT; fold 1/sqrt(64)=0.125 into Q
  transpose_pack<<<dim3(1, 16, 16), 256, 0, stream>>>(W_q, WqkvT, 64, 1024,
                                                      65536L, 64L * 1024, 0.125f);
  transpose_pack<<<dim3(1, 16, 16), 256, 0, stream>>>(W_k, WqkvT + 1024L * 1024, 64, 1024,
                                                      65536L, 64L * 1024, 1.0f);
  transpose_pack<<<dim3(16, 16, 1), 256, 0, stream>>>(W_v, WqkvT + 2048L * 1024, 1024, 1024,
                                                      0L, 0L, 1.0f);
  transpose_pack<<<dim3(16, 16, 1), 256, 0, stream>>>(W_o, WoT, 1024, 1024,
                                                      0L, 0L, 1.0f);
  // QKV projection: [8192,1024] x [1024,3072]
  gemm128<0, false><<<dim3(24, 64, 1), 256, 0, stream>>>(
      Xb, WqkvT, 8192, 3072, 1024, 0L, 0L, Qb, Kb, Vt, nullptr, 0L, nullptr);
  // masked softmax, head-avg
  attn16<<<dim3(32, 8), 256, 0, stream>>>(Qb, Kb, mask, out + 8388608L, attnb);
  // Hout = attn_avg @ V  (causal K-limit), per batch
  gemm128<1, true><<<dim3(8, 8, 8), 256, 0, stream>>>(
      attnb, Vt, 1024, 1024, 1024, 1048576L, 1048576L,
      nullptr, nullptr, nullptr, Houtb, 1048576L, nullptr);
  // output = Hout @ W_o
  gemm128<2, false><<<dim3(8, 64, 1), 256, 0, stream>>>(
      Houtb, WoT, 8192, 1024, 1024, 0L, 0L,
      nullptr, nullptr, nullptr, nullptr, 0L, out);
}

// Round 2
// 314.288 us; speedup vs baseline: 1.2581x; 1.2581x over previous
//
#include <hip/hip_runtime.h>

typedef unsigned short ushort;
typedef __bf16 bf16x8 __attribute__((ext_vector_type(8)));
typedef float f32x4 __attribute__((ext_vector_type(4)));
typedef unsigned short us8v __attribute__((ext_vector_type(8)));

__device__ __forceinline__ ushort f2bf(float f) {
  unsigned u = __builtin_bit_cast(unsigned, f);
  u += 0x7FFFu + ((u >> 16) & 1u);
  return (ushort)(u >> 16);
}

__device__ __forceinline__ bf16x8 ld_bf16x8(const ushort* p) {
  uint4 v = *(const uint4*)p;
  return __builtin_bit_cast(bf16x8, v);
}

// async global->LDS, 16B per lane (dest must be linear: base + lane*16)
__device__ __forceinline__ void gl16(const ushort* g, ushort* l) {
  __builtin_amdgcn_global_load_lds(
      (const __attribute__((address_space(1))) void*)g,
      (__attribute__((address_space(3))) void*)l, 16, 0, 0);
}

// ---------------- pack X fp32 -> bf16 ----------------
__global__ __launch_bounds__(256) void pack_x(const float* __restrict__ in,
                                              ushort* __restrict__ out) {
  long i = (long)blockIdx.x * 256 + threadIdx.x;
  const float4* s = (const float4*)in;
  float4 a = s[i * 2], b = s[i * 2 + 1];
  us8v o;
  o[0] = f2bf(a.x); o[1] = f2bf(a.y); o[2] = f2bf(a.z); o[3] = f2bf(a.w);
  o[4] = f2bf(b.x); o[5] = f2bf(b.y); o[6] = f2bf(b.z); o[7] = f2bf(b.w);
  *(us8v*)&out[i * 8] = o;
}

// ---------------- transpose+pack weights: dst[c][r] = src[r][c]*scale (bf16) ----
__global__ __launch_bounds__(256) void transpose_pack(
    const float* __restrict__ src, ushort* __restrict__ dst,
    int sC, int dLd, long sBatch, long dBatch, float scale) {
  src += (long)blockIdx.z * sBatch;
  dst += (long)blockIdx.z * dBatch;
  const int r0 = blockIdx.y * 64, c0 = blockIdx.x * 64;
  __shared__ ushort T[64 * 68];
  const int t = threadIdx.x;
#pragma unroll
  for (int i = 0; i < 4; ++i) {
    int ch = t + 256 * i;
    int r = ch >> 4, c4 = ch & 15;
    float4 v = *(const float4*)&src[(long)(r0 + r) * sC + c0 + c4 * 4];
    T[(c4 * 4 + 0) * 68 + r] = f2bf(v.x * scale);
    T[(c4 * 4 + 1) * 68 + r] = f2bf(v.y * scale);
    T[(c4 * 4 + 2) * 68 + r] = f2bf(v.z * scale);
    T[(c4 * 4 + 3) * 68 + r] = f2bf(v.w * scale);
  }
  __syncthreads();
#pragma unroll
  for (int i = 0; i < 4; ++i) {
    int ch = t + 256 * i;
    int c = ch >> 4, r4 = ch & 15;
    ushort4 o;
    o.x = T[c * 68 + r4 * 4 + 0];
    o.y = T[c * 68 + r4 * 4 + 1];
    o.z = T[c * 68 + r4 * 4 + 2];
    o.w = T[c * 68 + r4 * 4 + 3];
    *(ushort4*)&dst[(long)(c0 + c) * dLd + r0 + r4 * 4] = o;
  }
}

// ---------------- 128x128 bf16 MFMA GEMM (m97 structure), C = A * Bt^T --------
// EPI 0: scatter to Q/K ([B,H,S,64]) and Vt ([B,D,S]); EPI 1: bf16 C; EPI 2: fp32 C
template <int EPI, bool CAUSAL>
__global__ __launch_bounds__(256) void gemm128(
    const ushort* __restrict__ A, const ushort* __restrict__ Bt,
    int M, int N, int K, long aB, long bB,
    ushort* __restrict__ O_q, ushort* __restrict__ O_k, ushort* __restrict__ O_v,
    ushort* __restrict__ O_b, long oB,
    float* __restrict__ O_f) {
  __shared__ __align__(16) ushort As[128 * 64];
  __shared__ __align__(16) ushort Bs[128 * 64];
  const int tid = threadIdx.x;
  const int lane = tid & 63, w = tid >> 6;
  const int lr = lane & 15, lg = lane >> 4;
  const int row0 = blockIdx.y * 128, col0 = blockIdx.x * 128;
  const int z = blockIdx.z;
  A += (long)z * aB;
  Bt += (long)z * bB;
  const int wr = (w >> 1) * 64, wc = (w & 1) * 64;

  f32x4 acc[4][4] = {};
  const int kmax = CAUSAL ? (K < row0 + 128 ? K : row0 + 128) : K;
  for (int k0 = 0; k0 < kmax; k0 += 64) {
    __syncthreads();
#pragma unroll
    for (int i = 0; i < 4; ++i) {
      int c = i * 256 + tid;          // 16B chunk id, 0..1023
      int r = c >> 3, k8 = c & 7;
      gl16(&A[(long)(row0 + r) * K + k0 + k8 * 8], &As[c * 8]);
      gl16(&Bt[(long)(col0 + r) * K + k0 + k8 * 8], &Bs[c * 8]);
    }
    __syncthreads();  // implicit vmcnt(0) drains global_load_lds
#pragma unroll
    for (int kk = 0; kk < 2; ++kk) {
      bf16x8 af[4], bfr[4];
#pragma unroll
      for (int m = 0; m < 4; ++m)
        af[m] = ld_bf16x8(&As[(wr + m * 16 + lr) * 64 + kk * 32 + lg * 8]);
#pragma unroll
      for (int n = 0; n < 4; ++n)
        bfr[n] = ld_bf16x8(&Bs[(wc + n * 16 + lr) * 64 + kk * 32 + lg * 8]);
#pragma unroll
      for (int m = 0; m < 4; ++m)
#pragma unroll
        for (int n = 0; n < 4; ++n)
          acc[m][n] = __builtin_amdgcn_mfma_f32_16x16x32_bf16(af[m], bfr[n], acc[m][n], 0, 0, 0);
    }
  }

#pragma unroll
  for (int m = 0; m < 4; ++m)
#pragma unroll
    for (int n = 0; n < 4; ++n)
#pragma unroll
      for (int r = 0; r < 4; ++r) {
        int gr = row0 + wr + m * 16 + lg * 4 + r;
        int gc = col0 + wc + n * 16 + lr;
        float v = acc[m][n][r];
        if (EPI == 0) {
          int b = gr >> 10, s = gr & 1023;
          if (gc < 1024) {
            int h = gc >> 6, kq = gc & 63;
            O_q[(((long)(b * 16 + h) << 10) + s) * 64 + kq] = f2bf(v);
          } else if (gc < 2048) {
            int n2 = gc - 1024;
            int h = n2 >> 6, kq = n2 & 63;
            O_k[(((long)(b * 16 + h) << 10) + s) * 64 + kq] = f2bf(v);
          } else {
            int e = gc - 2048;
            O_v[((long)(b << 10) + e) * 1024 + s] = f2bf(v);
          }
        } else if (EPI == 1) {
          (O_b + (long)z * oB)[(long)gr * N + gc] = f2bf(v);
        } else {
          O_f[(long)gr * N + gc] = v;
        }
      }
}

// ---------------- fused masked softmax, head-averaged attention (v2) ----------
// grid (32, B), 512 threads = 8 waves. Block pairs q-tiles (p, 63-p), 16 q-rows.
// No K/Q LDS staging: per-wave direct global->reg fragment loads; 2 barriers/head.
__global__ __launch_bounds__(512) void attn16(
    const ushort* __restrict__ Qb, const ushort* __restrict__ Kb,
    const float* __restrict__ mask, float* __restrict__ attn_out,
    ushort* __restrict__ attnb) {
  __shared__ float redM[2][8][16];
  __shared__ float redS[2][8][16];
  const int tid = threadIdx.x;
  const int lane = tid & 63, w = tid >> 6;   // w = 0..7, owns s-cols w*16+lr per 128-tile
  const int lr = lane & 15, lg = lane >> 4;
  const int b = blockIdx.y;

#pragma unroll 1
  for (int pi = 0; pi < 2; ++pi) {
    const int qt = pi ? (63 - (int)blockIdx.x) : (int)blockIdx.x;
    const int q0 = qt * 16;

    float mq[4], ms[8];
#pragma unroll
    for (int r = 0; r < 4; ++r) mq[r] = mask[b * 1024 + q0 + lg * 4 + r];
#pragma unroll
    for (int t = 0; t < 8; ++t) ms[t] = mask[b * 1024 + t * 128 + w * 16 + lr];

    f32x4 acc[8] = {};
#pragma unroll 1
    for (int h = 0; h < 16; ++h) {
      const long hb = ((long)(b * 16 + h)) << 10;
      const bf16x8 qf0 = ld_bf16x8(&Qb[(hb + q0 + lr) * 64 + lg * 8]);
      const bf16x8 qf1 = ld_bf16x8(&Qb[(hb + q0 + lr) * 64 + 32 + lg * 8]);
      f32x4 sc[8];
      float pm[4] = {-3e38f, -3e38f, -3e38f, -3e38f};
#pragma unroll
      for (int t = 0; t < 8; ++t) {
        const int sb = t * 128 + w * 16;
        if (sb <= q0 + 15) {                 // wave-uniform causal chunk skip
          bf16x8 kf0 = ld_bf16x8(&Kb[(hb + sb + lr) * 64 + lg * 8]);
          bf16x8 kf1 = ld_bf16x8(&Kb[(hb + sb + lr) * 64 + 32 + lg * 8]);
          f32x4 d = {};
          d = __builtin_amdgcn_mfma_f32_16x16x32_bf16(qf0, kf0, d, 0, 0, 0);
          d = __builtin_amdgcn_mfma_f32_16x16x32_bf16(qf1, kf1, d, 0, 0, 0);
#pragma unroll
          for (int r = 0; r < 4; ++r) {
            int s = sb + lr, q = q0 + lg * 4 + r;
            float v = d[r] - 1e9f * (1.0f - mq[r] * ms[t]);
            v = (s <= q) ? v : -3e38f;
            d[r] = v;
            pm[r] = fmaxf(pm[r], v);
          }
          sc[t] = d;
        }
      }
      // row max: reduce over lr (s within strip), then across 8 waves via LDS
#pragma unroll
      for (int r = 0; r < 4; ++r) {
        pm[r] = fmaxf(pm[r], __shfl_xor(pm[r], 1));
        pm[r] = fmaxf(pm[r], __shfl_xor(pm[r], 2));
        pm[r] = fmaxf(pm[r], __shfl_xor(pm[r], 4));
        pm[r] = fmaxf(pm[r], __shfl_xor(pm[r], 8));
      }
      if (lr == 0) {
#pragma unroll
        for (int r = 0; r < 4; ++r) redM[h & 1][w][lg * 4 + r] = pm[r];
      }
      __syncthreads();
      float mx[4], ps[4] = {0.f, 0.f, 0.f, 0.f};
#pragma unroll
      for (int r = 0; r < 4; ++r) {
        float m = redM[h & 1][0][lg * 4 + r];
#pragma unroll
        for (int ww = 1; ww < 8; ++ww) m = fmaxf(m, redM[h & 1][ww][lg * 4 + r]);
        mx[r] = m;
      }
#pragma unroll
      for (int t = 0; t < 8; ++t) {
        const int sb = t * 128 + w * 16;
        if (sb <= q0 + 15) {
#pragma unroll
          for (int r = 0; r < 4; ++r) {
            float e = __expf(sc[t][r] - mx[r]);
            sc[t][r] = e;
            ps[r] += e;
          }
        }
      }
#pragma unroll
      for (int r = 0; r < 4; ++r) {
        ps[r] += __shfl_xor(ps[r], 1);
        ps[r] += __shfl_xor(ps[r], 2);
        ps[r] += __shfl_xor(ps[r], 4);
        ps[r] += __shfl_xor(ps[r], 8);
      }
      if (lr == 0) {
#pragma unroll
        for (int r = 0; r < 4; ++r) redS[h & 1][w][lg * 4 + r] = ps[r];
      }
      __syncthreads();
#pragma unroll
      for (int r = 0; r < 4; ++r) {
        float tot = 0.f;
#pragma unroll
        for (int ww = 0; ww < 8; ++ww) tot += redS[h & 1][ww][lg * 4 + r];
        float rinv = 1.0f / tot;
#pragma unroll
        for (int t = 0; t < 8; ++t) {
          const int sb = t * 128 + w * 16;
          if (sb <= q0 + 15) acc[t][r] += sc[t][r] * rinv;
        }
      }
    }  // heads

    // write fp32 attn_avg (d_out) + bf16 copy (ws); untouched chunks = exact zeros
#pragma unroll
    for (int t = 0; t < 8; ++t) {
      int s = t * 128 + w * 16 + lr;
#pragma unroll
      for (int r = 0; r < 4; ++r) {
        int q = q0 + lg * 4 + r;
        float v = acc[t][r] * 0.0625f;
        long o = ((long)(b * 1024 + q) << 10) + s;
        attn_out[o] = v;
        attnb[o] = f2bf(v);
      }
    }
  }
}

// ---------------- launch ----------------
extern "C" void kernel_launch(void* const* d_in, const int* in_sizes, int n_in,
                              void* d_out, int out_size, void* d_ws, size_t ws_size,
                              hipStream_t stream) {
  const float* inputs = (const float*)d_in[0];
  const float* mask   = (const float*)d_in[1];
  const float* W_q    = (const float*)d_in[2];
  const float* W_k    = (const float*)d_in[3];
  const float* W_v    = (const float*)d_in[4];
  const float* W_o    = (const float*)d_in[5];
  float* out = (float*)d_out;

  ushort* Xb    = (ushort*)d_ws;            // [8192][1024]
  ushort* WqkvT = Xb + 8192L * 1024;        // [3072][1024]  (B^T layout)
  ushort* WoT   = WqkvT + 3072L * 1024;     // [1024][1024]
  ushort* Qb    = WoT + 1024L * 1024;       // [B,H,S,64]
  ushort* Kb    = Qb + 8L * 16 * 1024 * 64; // [B,H,S,64]
  ushort* Vt    = Kb + 8L * 16 * 1024 * 64; // [B,D,S]
  ushort* attnb = Vt + 8L * 1024 * 1024;    // [B,S,S]
  ushort* Houtb = attnb + 8L * 1024 * 1024; // [B,S,D]

  pack_x<<<4096, 256, 0, stream>>>(inputs, Xb);
  transpose_pack<<<dim3(1, 16, 16), 256, 0, stream>>>(W_q, WqkvT, 64, 1024,
                                                      65536L, 64L * 1024, 0.125f);
  transpose_pack<<<dim3(1, 16, 16), 256, 0, stream>>>(W_k, WqkvT + 1024L * 1024, 64, 1024,
                                                      65536L, 64L * 1024, 1.0f);
  transpose_pack<<<dim3(16, 16, 1), 256, 0, stream>>>(W_v, WqkvT + 2048L * 1024, 1024, 1024,
                                                      0L, 0L, 1.0f);
  transpose_pack<<<dim3(16, 16, 1), 256, 0, stream>>>(W_o, WoT, 1024, 1024,
                                                      0L, 0L, 1.0f);
  // QKV projection: [8192,1024] x [1024,3072]
  gemm128<0, false><<<dim3(24, 64, 1), 256, 0, stream>>>(
      Xb, WqkvT, 8192, 3072, 1024, 0L, 0L, Qb, Kb, Vt, nullptr, 0L, nullptr);
  // masked softmax, head-avg
  attn16<<<dim3(32, 8), 512, 0, stream>>>(Qb, Kb, mask, out + 8388608L, attnb);
  // Hout = attn_avg @ V  (causal K-limit), per batch
  gemm128<1, true><<<dim3(8, 8, 8), 256, 0, stream>>>(
      attnb, Vt, 1024, 1024, 1024, 1048576L, 1048576L,
      nullptr, nullptr, nullptr, Houtb, 1048576L, nullptr);
  // output = Hout @ W_o
  gemm128<2, false><<<dim3(8, 64, 1), 256, 0, stream>>>(
      Houtb, WoT, 8192, 1024, 1024, 0L, 0L,
      nullptr, nullptr, nullptr, nullptr, 0L, out);
}